// Round 2
// 269.791 us; speedup vs baseline: 1.0936x; 1.0936x over previous
//
#include <hip/hip_runtime.h>
#include <math.h>

#define NB 4
#define NC 64
#define NL 1024   // 32x32 kernel-patch grid
#define NP 3969   // 63x63 correlation positions
#define PHW 63

typedef unsigned short ushort_t;
typedef __attribute__((ext_vector_type(8))) short short8;
typedef __attribute__((ext_vector_type(16))) float floatx16;

// A' per b: 32 rtiles * 64 kchunks * 64 lanes * 8 = 2^20 ushorts
#define A_BSTRIDE 1048576
// B' per b: 128 rtiles (4096 rows, padded for 256-wide p-tiles) * 64 * 512
#define B_BSTRIDE 4194304

// ---------------- kernel 1: per-(b,c) inverse L2 norm of b ----------------
__global__ __launch_bounds__(256) void norm_kernel(const float* __restrict__ bsrc,
                                                   float* __restrict__ invn) {
    int bc = blockIdx.x;  // 0..255
    const float* src = bsrc + (size_t)bc * 4096;
    float s = 0.f;
    for (int i = threadIdx.x; i < 4096; i += 256) { float v = src[i]; s += v * v; }
#pragma unroll
    for (int off = 32; off > 0; off >>= 1) s += __shfl_down(s, off, 64);
    __shared__ float part[4];
    if ((threadIdx.x & 63) == 0) part[threadIdx.x >> 6] = s;
    __syncthreads();
    if (threadIdx.x == 0) {
        float t = part[0] + part[1] + part[2] + part[3];
        invn[bc] = 1.0f / sqrtf(t + 1e-8f);
    }
}

// ---------------- kernel 2: patch means of (1-mask) -----------------------
__global__ __launch_bounds__(256) void stats_kernel(const float* __restrict__ mask,
                                                    float* __restrict__ mmk,
                                                    float* __restrict__ mmp) {
    int id = blockIdx.x * 256 + threadIdx.x;
    if (id < NB * NL) {
        int b = id >> 10, l = id & 1023;
        int lh = l >> 5, lw = l & 31;
        const float* m = mask + b * 4096;
        float s = 0.f;
#pragma unroll
        for (int i = 0; i < 4; ++i) {
            int r = min(max(2 * lh - 1 + i, 0), 63);
#pragma unroll
            for (int j = 0; j < 4; ++j) {
                int c = min(max(2 * lw - 1 + j, 0), 63);
                s += 1.0f - m[r * 64 + c];
            }
        }
        mmk[id] = s * (1.0f / 16.0f);
    } else {
        int id2 = id - NB * NL;
        if (id2 < NB * NP) {
            int b = id2 / NP, p = id2 - b * NP;
            int ph = p / PHW, pw = p - ph * PHW;
            const float* m = mask + b * 4096;
            float s = 0.f;
#pragma unroll
            for (int i = 0; i < 4; ++i) {
                int r = min(max(ph - 1 + i, 0), 63);
#pragma unroll
                for (int j = 0; j < 4; ++j) {
                    int c = min(max(pw - 1 + j, 0), 63);
                    s += 1.0f - m[r * 64 + c];
                }
            }
            mmp[id2] = s * (1.0f / 16.0f);
        }
    }
}

// ------------- split helper: fp32 -> bf16 hi + bf16 residual --------------
__device__ inline void split_bf16(float v, ushort_t& hv, ushort_t& lv) {
    unsigned u = __float_as_uint(v);
    unsigned rr = u + 0x7FFFu + ((u >> 16) & 1u);
    hv = (ushort_t)(rr >> 16);
    float fh = __uint_as_float(((unsigned)hv) << 16);
    float remv = v - fh;
    unsigned u2 = __float_as_uint(remv);
    unsigned rr2 = u2 + 0x7FFFu + ((u2 >> 16) & 1u);
    lv = (ushort_t)(rr2 >> 16);
}

// fragment-order address for (row, kchunk)
__device__ inline int frag_addr(int row, int kc) {
    return ((row >> 5) * 64 + kc) * 512 + (row & 31) * 8;
}

// ---------------- kernel 3a: split A into fragment order ------------------
__global__ __launch_bounds__(256) void splitA_kernel(const float* __restrict__ bsrc,
                                                     const float* __restrict__ invn,
                                                     ushort_t* __restrict__ Ahi,
                                                     ushort_t* __restrict__ Alo) {
    __shared__ float fl[32 * 257];
    int lh = blockIdx.x, b = blockIdx.y, chalf = blockIdx.z;
    int t = threadIdx.x;
#pragma unroll
    for (int q = 0; q < 32; ++q) {
        int idx = t + (q << 8);
        int cl = idx >> 8, rem = idx & 255;
        int i = rem >> 6, s = rem & 63;
        int c = (chalf << 5) + cl;
        int r = min(max(2 * lh - 1 + i, 0), 63);
        fl[cl * 257 + rem] = bsrc[(((size_t)((b << 6) + c)) << 12) + (r << 6) + s];
    }
    __syncthreads();
    ushort_t* Ah = Ahi + (size_t)b * A_BSTRIDE;
    ushort_t* Al = Alo + (size_t)b * A_BSTRIDE;
#pragma unroll
    for (int q = 0; q < 4; ++q) {
        int pair = t + (q << 8);         // 0..1023
        int lw = pair & 31, cl = pair >> 5;
        int c = (chalf << 5) + cl;
        float scale = invn[(b << 6) + c];
        const float* row = fl + cl * 257;
        __align__(16) ushort_t h[16];
        __align__(16) ushort_t lo[16];
#pragma unroll
        for (int i = 0; i < 4; ++i)
#pragma unroll
            for (int j = 0; j < 4; ++j) {
                int s = min(max(2 * lw - 1 + j, 0), 63);
                split_bf16(row[i * 64 + s] * scale, h[i * 4 + j], lo[i * 4 + j]);
            }
        int a = (lh * 64 + c) * 512 + lw * 8;
        *(uint4*)(Ah + a)       = *(uint4*)h;
        *(uint4*)(Ah + a + 256) = *(uint4*)(h + 8);
        *(uint4*)(Al + a)       = *(uint4*)lo;
        *(uint4*)(Al + a + 256) = *(uint4*)(lo + 8);
    }
}

// ------------- kernel 3b-pre: zero B' pad rows 3968..4095 -----------------
__global__ __launch_bounds__(256) void padB_kernel(ushort_t* __restrict__ Bhi,
                                                   ushort_t* __restrict__ Blo) {
    // zero rtiles 124..127 (rows 3968..4095) for all b, both matrices
    // region per (b,mat): 4 rtiles * 32768 ushorts = 16384 uint4
    int idx = blockIdx.x * 256 + threadIdx.x;   // 0..131071 (512 blocks)
    int b = idx >> 15;
    int r = idx & 32767;
    int mat = r >> 14;
    int o = r & 16383;
    ushort_t* base = (mat ? Blo : Bhi) + (size_t)b * B_BSTRIDE + 124 * 32768;
    uint4 z = {0u, 0u, 0u, 0u};
    ((uint4*)base)[o] = z;
}

// ---------------- kernel 3b: split B into fragment order ------------------
__global__ __launch_bounds__(256) void splitB_kernel(const float* __restrict__ fsrc,
                                                     ushort_t* __restrict__ Bhi,
                                                     ushort_t* __restrict__ Blo) {
    __shared__ float fl[32 * 257];
    int ph = blockIdx.x, b = blockIdx.y, chalf = blockIdx.z;
    int t = threadIdx.x;
#pragma unroll
    for (int q = 0; q < 32; ++q) {
        int idx = t + (q << 8);
        int cl = idx >> 8, rem = idx & 255;
        int i = rem >> 6, s = rem & 63;
        int c = (chalf << 5) + cl;
        int r = min(max(ph - 1 + i, 0), 63);
        fl[cl * 257 + rem] = fsrc[(((size_t)((b << 6) + c)) << 12) + (r << 6) + s];
    }
    __syncthreads();
    ushort_t* Bh = Bhi + (size_t)b * B_BSTRIDE;
    ushort_t* Bl = Blo + (size_t)b * B_BSTRIDE;
#pragma unroll
    for (int q = 0; q < 8; ++q) {
        int pair = t + (q << 8);          // 0..2047
        int pw = pair & 63, cl = pair >> 6;
        if (pw < PHW) {
            int c = (chalf << 5) + cl;
            const float* row = fl + cl * 257;
            __align__(16) ushort_t h[16];
            __align__(16) ushort_t lo[16];
#pragma unroll
            for (int i = 0; i < 4; ++i)
#pragma unroll
                for (int j = 0; j < 4; ++j) {
                    int s = min(max(pw - 1 + j, 0), 63);
                    split_bf16(row[i * 64 + s], h[i * 4 + j], lo[i * 4 + j]);
                }
            int p = ph * PHW + pw;
            int a = frag_addr(p, c);
            *(uint4*)(Bh + a)       = *(uint4*)h;
            *(uint4*)(Bh + a + 256) = *(uint4*)(h + 8);
            *(uint4*)(Bl + a)       = *(uint4*)lo;
            *(uint4*)(Bl + a + 256) = *(uint4*)(lo + 8);
        }
    }
}

// ---------------- kernel 4: 256x256-tile LDS-staged MFMA GEMM -------------
// 8 waves (2 l x 4 p), per-wave 128l x 64p, BK=32 double-buffered in LDS.
// Counted vmcnt(8): next chunk's 8 global_load_lds stay in flight across the
// barriers (T3+T4); raw s_barrier (no drain); setprio around MFMA (T5).
// Fragment layout in LDS = linear copy of the fragment-ordered A'/B', so all
// ds_read_b128 are base + lane*16B = conflict-free.
__global__ __launch_bounds__(512, 2) void gemm_kernel(
    const ushort_t* __restrict__ Ahi, const ushort_t* __restrict__ Alo,
    const ushort_t* __restrict__ Bhi, const ushort_t* __restrict__ Blo,
    float* __restrict__ Rt) {
    // [buf][matrix: Ah,Al,Bh,Bl][rtile 0..7][ks 0..1][512] : 128 KiB
    __shared__ ushort_t smem[2][4][8][2][512];
    int tid = threadIdx.x;
    int lane = tid & 63, w = tid >> 6;
    int wl = w >> 2, wp = w & 3;
    int bx = blockIdx.x, b = blockIdx.y;   // bx: 4 ltiles x 16 ptiles
    int L0 = (bx & 3) << 8;
    int P0 = (bx >> 2) << 8;

    // stage role: each wave stages one matrix, 4 rtiles x 2 ks = 8 loads/chunk
    int m = w >> 1;              // 0 Ahi, 1 Alo, 2 Bhi, 3 Blo
    int rt0 = (w & 1) << 2;
    const ushort_t* gbase;
    if (m == 0)      gbase = Ahi + (size_t)b * A_BSTRIDE + (size_t)(L0 >> 5) * 32768;
    else if (m == 1) gbase = Alo + (size_t)b * A_BSTRIDE + (size_t)(L0 >> 5) * 32768;
    else if (m == 2) gbase = Bhi + (size_t)b * B_BSTRIDE + (size_t)(P0 >> 5) * 32768;
    else             gbase = Blo + (size_t)b * B_BSTRIDE + (size_t)(P0 >> 5) * 32768;
    gbase += (size_t)(lane << 3);
    int dst0 = ((((m << 3) + rt0) << 1)) * 512;   // wave-uniform LDS elem offset

    ushort_t* buf0 = &smem[0][0][0][0][0];
    ushort_t* buf1 = &smem[1][0][0][0][0];

#define STAGE(dstp, t)                                                                     \
    do {                                                                                   \
        int kb = (t) << 1;                                                                 \
        _Pragma("unroll")                                                                  \
        for (int j = 0; j < 4; ++j)                                                        \
            _Pragma("unroll")                                                              \
            for (int ks = 0; ks < 2; ++ks)                                                 \
                __builtin_amdgcn_global_load_lds(                                          \
                    (const __attribute__((address_space(1))) void*)(                       \
                        gbase + (size_t)(rt0 + j) * 32768 + (size_t)(kb + ks) * 512),      \
                    (__attribute__((address_space(3))) void*)(                             \
                        (dstp) + dst0 + (((j << 1) + ks) * 512)),                          \
                    16, 0, 0);                                                             \
    } while (0)

    floatx16 acc[2][4];
#pragma unroll
    for (int i = 0; i < 2; ++i)
#pragma unroll
        for (int j = 0; j < 4; ++j)
#pragma unroll
            for (int r = 0; r < 16; ++r) acc[i][j][r] = 0.f;

    STAGE(buf0, 0);
    ushort_t* cur = buf0;
    ushort_t* nxt = buf1;

    int aoff = (wl << 2) * 1024;           // A rtile base for this wave (elems)
    int boff = 16384 + (wp << 1) * 1024;   // Bhi rtile base

    for (int t = 0; t < 32; ++t) {
        asm volatile("" ::: "memory");
        __builtin_amdgcn_s_barrier();            // B1: all reads of buf[nxt] done
        asm volatile("" ::: "memory");
        if (t < 31) {
            STAGE(nxt, t + 1);                   // 8 loads into the freed buffer
            asm volatile("s_waitcnt vmcnt(8)" ::: "memory");   // chunk t landed
        } else {
            asm volatile("s_waitcnt vmcnt(0)" ::: "memory");
        }
        __builtin_amdgcn_s_barrier();            // B2: chunk t visible to all
        asm volatile("" ::: "memory");

        const ushort_t* rb = cur + (lane << 3);
#pragma unroll
        for (int ks = 0; ks < 2; ++ks) {
            short8 ah[4], al[4], bh[2], bl[2];
#pragma unroll
            for (int lt = 0; lt < 4; ++lt) {
                ah[lt] = *(const short8*)(rb + aoff + lt * 1024 + ks * 512);
                al[lt] = *(const short8*)(rb + 8192 + aoff + lt * 1024 + ks * 512);
            }
#pragma unroll
            for (int pt = 0; pt < 2; ++pt) {
                bh[pt] = *(const short8*)(rb + boff + pt * 1024 + ks * 512);
                bl[pt] = *(const short8*)(rb + 8192 + boff + pt * 1024 + ks * 512);
            }
            __builtin_amdgcn_s_setprio(1);
#pragma unroll
            for (int pt = 0; pt < 2; ++pt)
#pragma unroll
                for (int lt = 0; lt < 4; ++lt) {
                    acc[pt][lt] = __builtin_amdgcn_mfma_f32_32x32x16_bf16(bh[pt], ah[lt], acc[pt][lt], 0, 0, 0);
                    acc[pt][lt] = __builtin_amdgcn_mfma_f32_32x32x16_bf16(bh[pt], al[lt], acc[pt][lt], 0, 0, 0);
                    acc[pt][lt] = __builtin_amdgcn_mfma_f32_32x32x16_bf16(bl[pt], ah[lt], acc[pt][lt], 0, 0, 0);
                }
            __builtin_amdgcn_s_setprio(0);
        }
        ushort_t* tmp = cur; cur = nxt; nxt = tmp;
    }
#undef STAGE

    int x = lane & 31, kg = lane >> 5;
    int pw0 = P0 + (wp << 6);
    int lw0 = L0 + (wl << 7);
#pragma unroll
    for (int pt = 0; pt < 2; ++pt)
#pragma unroll
        for (int lt = 0; lt < 4; ++lt)
#pragma unroll
            for (int r = 0; r < 16; ++r) {
                int p = pw0 + (pt << 5) + (r & 3) + ((r >> 2) << 3) + (kg << 2);
                int l = lw0 + (lt << 5) + x;
                if (p < NP) Rt[((size_t)b * NP + p) * NL + l] = acc[pt][lt][r];
            }
}

// ------- kernel 5: fused diag1 + diag2 + mask + softmax, row output -------
__global__ __launch_bounds__(256) void softmax_fused_kernel(const float* __restrict__ Rt,
                                                            const float* __restrict__ mmkA,
                                                            const float* __restrict__ mmpA,
                                                            float* __restrict__ E) {
    __shared__ float ld0[1024], ld1[1024], ld2[1024];
    __shared__ float red[8];
    int p = blockIdx.x, b = blockIdx.y;
    int ph = p / PHW, pw = p - ph * PHW;
    int t = threadIdx.x;
    int lane = t & 63, w = t >> 6;
    int l0 = t << 2;

    bool okm = (p != 0), okp = (p != 3968);
    int Pm = (ph > 0) ? p - 63 : 3905 + pw;
    int Pp = (ph < 62) ? p + 63 : pw + 1;

    const float* Rb = Rt + (size_t)b * NP * NL;
#define BUILD(dst, q)                                                   \
    do {                                                                \
        const float* base = Rb + (size_t)(q) * NL;                      \
        float4 r = *(const float4*)(base + l0);                         \
        if ((q) > 0) {                                                  \
            const float* pm = base - NL;                                \
            r.x += (l0 > 0) ? pm[l0 - 1] : 0.f;                         \
            r.y += pm[l0];  r.z += pm[l0 + 1];  r.w += pm[l0 + 2];      \
        }                                                               \
        if ((q) < NP - 1) {                                             \
            const float* pp = base + NL;                                \
            r.x += pp[l0 + 1];  r.y += pp[l0 + 2];  r.z += pp[l0 + 3];  \
            r.w += (l0 + 4 < NL) ? pp[l0 + 4] : 0.f;                    \
        }                                                               \
        *(float4*)(dst + l0) = r;                                       \
    } while (0)

    BUILD(ld0, p);
    if (okm) BUILD(ld1, Pm);
    if (okp) BUILD(ld2, Pp);
#undef BUILD
    __syncthreads();

    float4 vc = *(const float4*)(ld0 + l0);
    float4 vm = {0.f, 0.f, 0.f, 0.f}, vp = {0.f, 0.f, 0.f, 0.f};
    if (okm) {
        if (l0 >= 32) vm = *(const float4*)(ld1 + l0 - 32);
        else {
            vm.x = (l0 == 0) ? 0.f : ld1[l0 + 991];
            vm.y = ld1[l0 + 992];
            vm.z = ld1[l0 + 993];
            vm.w = ld1[l0 + 994];
        }
    }
    if (okp) {
        if (l0 < 992) vp = *(const float4*)(ld2 + l0 + 32);
        else {
            vp.x = ld2[l0 - 991];
            vp.y = ld2[l0 - 990];
            vp.z = ld2[l0 - 989];
            vp.w = (l0 + 3 == 1023) ? 0.f : ld2[l0 - 988];
        }
    }
    float mmpv = mmpA[b * NP + p];
    float4 km = *(const float4*)(mmkA + b * NL + l0);
    float lg[4];
    float fsum[4] = {vc.x + vm.x + vp.x, vc.y + vm.y + vp.y,
                     vc.z + vm.z + vp.z, vc.w + vm.w + vp.w};
    float kk[4] = {km.x, km.y, km.z, km.w};
#pragma unroll
    for (int i = 0; i < 4; ++i) {
        float mmv = (((kk[i] > mmpv) && (mmpv > 0.5f)) || (kk[i] == 1.0f)) ? 1.0f : 0.0f;
        lg[i] = fsum[i] * mmv * 10.0f;
    }
    float mx = fmaxf(fmaxf(lg[0], lg[1]), fmaxf(lg[2], lg[3]));
#pragma unroll
    for (int off = 32; off >= 1; off >>= 1) mx = fmaxf(mx, __shfl_xor(mx, off, 64));
    if (lane == 0) red[w] = mx;
    __syncthreads();
    mx = fmaxf(fmaxf(red[0], red[1]), fmaxf(red[2], red[3]));
    float e[4];
    float s = 0.f;
#pragma unroll
    for (int i = 0; i < 4; ++i) { e[i] = expf(lg[i] - mx); s += e[i]; }
#pragma unroll
    for (int off = 32; off >= 1; off >>= 1) s += __shfl_xor(s, off, 64);
    if (lane == 0) red[4 + w] = s;
    __syncthreads();
    float rinv = 1.0f / (red[4] + red[5] + red[6] + red[7]);
    float4 ev = {e[0] * rinv, e[1] * rinv, e[2] * rinv, e[3] * rinv};
    *(float4*)(E + (((size_t)b * NP + p) << 10) + l0) = ev;
}

// ---------------- kernel 6: tiled transpose E[p][l] -> out[l][p] ----------
__global__ __launch_bounds__(256) void transpose_kernel(const float* __restrict__ E,
                                                        float* __restrict__ out) {
    __shared__ float tile[63 * 65];
    int pt = blockIdx.x;       // 0..62 : p0 = pt*63
    int lt = blockIdx.y;       // 0..15 : l0 = lt*64
    int b  = blockIdx.z;
    int t = threadIdx.x;
    int p0 = pt * 63, l0 = lt << 6;
    const float* Eb = E + ((size_t)b * NP << 10);
    {
        int j = t & 63, i4 = t >> 6;
#pragma unroll
        for (int k = 0; k < 16; ++k) {
            int i = (k << 2) + i4;
            if (i < 63) tile[i * 65 + j] = Eb[((size_t)(p0 + i) << 10) + l0 + j];
        }
    }
    __syncthreads();
    {
        int ii = t & 63, jj4 = t >> 6;
        if (ii < 63) {
#pragma unroll
            for (int k = 0; k < 16; ++k) {
                int jj = (k << 2) + jj4;
                out[((size_t)b * NL + l0 + jj) * NP + p0 + ii] = tile[ii * 65 + jj];
            }
        }
    }
}

extern "C" void kernel_launch(void* const* d_in, const int* in_sizes, int n_in,
                              void* d_out, int out_size, void* d_ws, size_t ws_size,
                              hipStream_t stream) {
    const float* f    = (const float*)d_in[0];
    const float* b    = (const float*)d_in[1];
    const float* mask = (const float*)d_in[2];
    float* out = (float*)d_out;

    // Rt lives in d_out (consumed by softmax before transpose overwrites out).
    float* Rt = (float*)d_out;

    // ws layout (floats): E at [16257024 .. 32514048); stats after.
    // A'/B' (~84 MB) occupy ws from 0 but are dead post-GEMM; E region is
    // written only by softmax (after GEMM completes).
    float* wsf = (float*)d_ws;
    float* E  = wsf + 16257024;
    ushort_t* Ahi = (ushort_t*)d_ws;
    ushort_t* Alo = Ahi + (size_t)NB * A_BSTRIDE;
    ushort_t* Bhi = Alo + (size_t)NB * A_BSTRIDE;
    ushort_t* Blo = Bhi + (size_t)NB * B_BSTRIDE;
    float* invn = wsf + 32514048;
    float* mmk = invn + 256;
    float* mmp = mmk + 4096;

    norm_kernel<<<dim3(256), dim3(256), 0, stream>>>(b, invn);
    stats_kernel<<<dim3(79), dim3(256), 0, stream>>>(mask, mmk, mmp);
    splitA_kernel<<<dim3(32, 4, 2), dim3(256), 0, stream>>>(b, invn, Ahi, Alo);
    padB_kernel<<<dim3(512), dim3(256), 0, stream>>>(Bhi, Blo);
    splitB_kernel<<<dim3(63, 4, 2), dim3(256), 0, stream>>>(f, Bhi, Blo);
    gemm_kernel<<<dim3(64, 4), dim3(512), 0, stream>>>(Ahi, Alo, Bhi, Blo, Rt);
    softmax_fused_kernel<<<dim3(3969, 4), dim3(256), 0, stream>>>(Rt, mmk, mmp, E);
    transpose_kernel<<<dim3(63, 16, 4), dim3(256), 0, stream>>>(E, out);
}

// Round 3
// 265.193 us; speedup vs baseline: 1.1125x; 1.0173x over previous
//
#include <hip/hip_runtime.h>
#include <math.h>

#define NB 4
#define NC 64
#define NL 1024   // 32x32 kernel-patch grid
#define NP 3969   // 63x63 correlation positions
#define PHW 63

typedef unsigned short ushort_t;
typedef __attribute__((ext_vector_type(8))) short short8;
typedef __attribute__((ext_vector_type(16))) float floatx16;

// A' per b: 32 rtiles * 64 kchunks * 64 lanes * 8 = 2^20 ushorts
#define A_BSTRIDE 1048576
// B' per b: 128 rtiles (4096 rows, padded for 256-wide p-tiles) * 64 * 512
#define B_BSTRIDE 4194304

// ---------------- kernel 1: fused prep = norm + stats + padB --------------
// blocks 0..255   : per-(b,c) inverse L2 norm of b
// blocks 256..334 : patch means of (1-mask) -> mmk, mmp
// blocks 335..846 : zero B' pad rows 3968..4095 (rtiles 124..127)
__global__ __launch_bounds__(256) void prep_kernel(const float* __restrict__ bsrc,
                                                   const float* __restrict__ mask,
                                                   float* __restrict__ invn,
                                                   float* __restrict__ mmk,
                                                   float* __restrict__ mmp,
                                                   ushort_t* __restrict__ Bhi,
                                                   ushort_t* __restrict__ Blo) {
    int blk = blockIdx.x;
    if (blk < 256) {
        const float* src = bsrc + (size_t)blk * 4096;
        float s = 0.f;
        for (int i = threadIdx.x; i < 4096; i += 256) { float v = src[i]; s += v * v; }
#pragma unroll
        for (int off = 32; off > 0; off >>= 1) s += __shfl_down(s, off, 64);
        __shared__ float part[4];
        if ((threadIdx.x & 63) == 0) part[threadIdx.x >> 6] = s;
        __syncthreads();
        if (threadIdx.x == 0) {
            float t = part[0] + part[1] + part[2] + part[3];
            invn[blk] = 1.0f / sqrtf(t + 1e-8f);
        }
    } else if (blk < 335) {
        int id = (blk - 256) * 256 + threadIdx.x;
        if (id < NB * NL) {
            int b = id >> 10, l = id & 1023;
            int lh = l >> 5, lw = l & 31;
            const float* m = mask + b * 4096;
            float s = 0.f;
#pragma unroll
            for (int i = 0; i < 4; ++i) {
                int r = min(max(2 * lh - 1 + i, 0), 63);
#pragma unroll
                for (int j = 0; j < 4; ++j) {
                    int c = min(max(2 * lw - 1 + j, 0), 63);
                    s += 1.0f - m[r * 64 + c];
                }
            }
            mmk[id] = s * (1.0f / 16.0f);
        } else {
            int id2 = id - NB * NL;
            if (id2 < NB * NP) {
                int b = id2 / NP, p = id2 - b * NP;
                int ph = p / PHW, pw = p - ph * PHW;
                const float* m = mask + b * 4096;
                float s = 0.f;
#pragma unroll
                for (int i = 0; i < 4; ++i) {
                    int r = min(max(ph - 1 + i, 0), 63);
#pragma unroll
                    for (int j = 0; j < 4; ++j) {
                        int c = min(max(pw - 1 + j, 0), 63);
                        s += 1.0f - m[r * 64 + c];
                    }
                }
                mmp[id2] = s * (1.0f / 16.0f);
            }
        }
    } else {
        // zero rtiles 124..127 (rows 3968..4095) for all b, both matrices
        int idx = (blk - 335) * 256 + threadIdx.x;   // 0..131071
        int b = idx >> 15;
        int r = idx & 32767;
        int mat = r >> 14;
        int o = r & 16383;
        ushort_t* base = (mat ? Blo : Bhi) + (size_t)b * B_BSTRIDE + 124 * 32768;
        uint4 z = {0u, 0u, 0u, 0u};
        ((uint4*)base)[o] = z;
    }
}

// ------------- split helper: fp32 -> bf16 hi + bf16 residual --------------
__device__ inline void split_bf16(float v, ushort_t& hv, ushort_t& lv) {
    unsigned u = __float_as_uint(v);
    unsigned rr = u + 0x7FFFu + ((u >> 16) & 1u);
    hv = (ushort_t)(rr >> 16);
    float fh = __uint_as_float(((unsigned)hv) << 16);
    float remv = v - fh;
    unsigned u2 = __float_as_uint(remv);
    unsigned rr2 = u2 + 0x7FFFu + ((u2 >> 16) & 1u);
    lv = (ushort_t)(rr2 >> 16);
}

// fragment-order address for (row, kchunk)
__device__ inline int frag_addr(int row, int kc) {
    return ((row >> 5) * 64 + kc) * 512 + (row & 31) * 8;
}

// ---------------- kernel 3a: split A into fragment order ------------------
__global__ __launch_bounds__(256) void splitA_kernel(const float* __restrict__ bsrc,
                                                     const float* __restrict__ invn,
                                                     ushort_t* __restrict__ Ahi,
                                                     ushort_t* __restrict__ Alo) {
    __shared__ float fl[32 * 257];
    int lh = blockIdx.x, b = blockIdx.y, chalf = blockIdx.z;
    int t = threadIdx.x;
#pragma unroll
    for (int q = 0; q < 32; ++q) {
        int idx = t + (q << 8);
        int cl = idx >> 8, rem = idx & 255;
        int i = rem >> 6, s = rem & 63;
        int c = (chalf << 5) + cl;
        int r = min(max(2 * lh - 1 + i, 0), 63);
        fl[cl * 257 + rem] = bsrc[(((size_t)((b << 6) + c)) << 12) + (r << 6) + s];
    }
    __syncthreads();
    ushort_t* Ah = Ahi + (size_t)b * A_BSTRIDE;
    ushort_t* Al = Alo + (size_t)b * A_BSTRIDE;
#pragma unroll
    for (int q = 0; q < 4; ++q) {
        int pair = t + (q << 8);         // 0..1023
        int lw = pair & 31, cl = pair >> 5;
        int c = (chalf << 5) + cl;
        float scale = invn[(b << 6) + c];
        const float* row = fl + cl * 257;
        __align__(16) ushort_t h[16];
        __align__(16) ushort_t lo[16];
#pragma unroll
        for (int i = 0; i < 4; ++i)
#pragma unroll
            for (int j = 0; j < 4; ++j) {
                int s = min(max(2 * lw - 1 + j, 0), 63);
                split_bf16(row[i * 64 + s] * scale, h[i * 4 + j], lo[i * 4 + j]);
            }
        int a = (lh * 64 + c) * 512 + lw * 8;
        *(uint4*)(Ah + a)       = *(uint4*)h;
        *(uint4*)(Ah + a + 256) = *(uint4*)(h + 8);
        *(uint4*)(Al + a)       = *(uint4*)lo;
        *(uint4*)(Al + a + 256) = *(uint4*)(lo + 8);
    }
}

// ---------------- kernel 3b: split B into fragment order ------------------
__global__ __launch_bounds__(256) void splitB_kernel(const float* __restrict__ fsrc,
                                                     ushort_t* __restrict__ Bhi,
                                                     ushort_t* __restrict__ Blo) {
    __shared__ float fl[32 * 257];
    int ph = blockIdx.x, b = blockIdx.y, chalf = blockIdx.z;
    int t = threadIdx.x;
#pragma unroll
    for (int q = 0; q < 32; ++q) {
        int idx = t + (q << 8);
        int cl = idx >> 8, rem = idx & 255;
        int i = rem >> 6, s = rem & 63;
        int c = (chalf << 5) + cl;
        int r = min(max(ph - 1 + i, 0), 63);
        fl[cl * 257 + rem] = fsrc[(((size_t)((b << 6) + c)) << 12) + (r << 6) + s];
    }
    __syncthreads();
    ushort_t* Bh = Bhi + (size_t)b * B_BSTRIDE;
    ushort_t* Bl = Blo + (size_t)b * B_BSTRIDE;
#pragma unroll
    for (int q = 0; q < 8; ++q) {
        int pair = t + (q << 8);          // 0..2047
        int pw = pair & 63, cl = pair >> 6;
        if (pw < PHW) {
            int c = (chalf << 5) + cl;
            const float* row = fl + cl * 257;
            __align__(16) ushort_t h[16];
            __align__(16) ushort_t lo[16];
#pragma unroll
            for (int i = 0; i < 4; ++i)
#pragma unroll
                for (int j = 0; j < 4; ++j) {
                    int s = min(max(pw - 1 + j, 0), 63);
                    split_bf16(row[i * 64 + s], h[i * 4 + j], lo[i * 4 + j]);
                }
            int p = ph * PHW + pw;
            int a = frag_addr(p, c);
            *(uint4*)(Bh + a)       = *(uint4*)h;
            *(uint4*)(Bh + a + 256) = *(uint4*)(h + 8);
            *(uint4*)(Bl + a)       = *(uint4*)lo;
            *(uint4*)(Bl + a + 256) = *(uint4*)(lo + 8);
        }
    }
}

// ---------------- kernel 4: 256x256-tile LDS-staged MFMA GEMM -------------
// 8 waves (2 l x 4 p), per-wave 128l x 64p, BK=32 double-buffered in LDS.
// Counted vmcnt(8) (T4); raw s_barrier; setprio around MFMA (T5).
// XCD-chunked work-id swizzle (T1): xcd = bid%8 gets 32 consecutive wids
// = {1 b, 8 ptiles, 4 ltiles} -> per-K-step L2 footprint 384 KB/XCD, so
// co-resident blocks on an XCD share panel fetches out of L2 instead of
// re-streaming 512 MB from L3/HBM.
__global__ __launch_bounds__(512, 2) void gemm_kernel(
    const ushort_t* __restrict__ Ahi, const ushort_t* __restrict__ Alo,
    const ushort_t* __restrict__ Bhi, const ushort_t* __restrict__ Blo,
    float* __restrict__ Rt) {
    // [buf][matrix: Ah,Al,Bh,Bl][rtile 0..7][ks 0..1][512] : 128 KiB
    __shared__ ushort_t smem[2][4][8][2][512];
    int tid = threadIdx.x;
    int lane = tid & 63, w = tid >> 6;
    int wl = w >> 2, wp = w & 3;
    int bid = blockIdx.x;                      // 0..255
    int wid = ((bid & 7) << 5) + (bid >> 3);   // bijective XCD-chunk remap
    int b = wid >> 6;
    int bx = wid & 63;                         // 4 ltiles x 16 ptiles
    int L0 = (bx & 3) << 8;
    int P0 = (bx >> 2) << 8;

    // stage role: each wave stages one matrix, 4 rtiles x 2 ks = 8 loads/chunk
    int m = w >> 1;              // 0 Ahi, 1 Alo, 2 Bhi, 3 Blo
    int rt0 = (w & 1) << 2;
    const ushort_t* gbase;
    if (m == 0)      gbase = Ahi + (size_t)b * A_BSTRIDE + (size_t)(L0 >> 5) * 32768;
    else if (m == 1) gbase = Alo + (size_t)b * A_BSTRIDE + (size_t)(L0 >> 5) * 32768;
    else if (m == 2) gbase = Bhi + (size_t)b * B_BSTRIDE + (size_t)(P0 >> 5) * 32768;
    else             gbase = Blo + (size_t)b * B_BSTRIDE + (size_t)(P0 >> 5) * 32768;
    gbase += (size_t)(lane << 3);
    int dst0 = ((((m << 3) + rt0) << 1)) * 512;   // wave-uniform LDS elem offset

    ushort_t* buf0 = &smem[0][0][0][0][0];
    ushort_t* buf1 = &smem[1][0][0][0][0];

#define STAGE(dstp, t)                                                                     \
    do {                                                                                   \
        int kb = (t) << 1;                                                                 \
        _Pragma("unroll")                                                                  \
        for (int j = 0; j < 4; ++j)                                                        \
            _Pragma("unroll")                                                              \
            for (int ks = 0; ks < 2; ++ks)                                                 \
                __builtin_amdgcn_global_load_lds(                                          \
                    (const __attribute__((address_space(1))) void*)(                       \
                        gbase + (size_t)(rt0 + j) * 32768 + (size_t)(kb + ks) * 512),      \
                    (__attribute__((address_space(3))) void*)(                             \
                        (dstp) + dst0 + (((j << 1) + ks) * 512)),                          \
                    16, 0, 0);                                                             \
    } while (0)

    floatx16 acc[2][4];
#pragma unroll
    for (int i = 0; i < 2; ++i)
#pragma unroll
        for (int j = 0; j < 4; ++j)
#pragma unroll
            for (int r = 0; r < 16; ++r) acc[i][j][r] = 0.f;

    STAGE(buf0, 0);
    ushort_t* cur = buf0;
    ushort_t* nxt = buf1;

    int aoff = (wl << 2) * 1024;           // A rtile base for this wave (elems)
    int boff = 16384 + (wp << 1) * 1024;   // Bhi rtile base

    for (int t = 0; t < 32; ++t) {
        asm volatile("" ::: "memory");
        __builtin_amdgcn_s_barrier();            // B1: all reads of buf[nxt] done
        asm volatile("" ::: "memory");
        if (t < 31) {
            STAGE(nxt, t + 1);                   // 8 loads into the freed buffer
            asm volatile("s_waitcnt vmcnt(8)" ::: "memory");   // chunk t landed
        } else {
            asm volatile("s_waitcnt vmcnt(0)" ::: "memory");
        }
        __builtin_amdgcn_s_barrier();            // B2: chunk t visible to all
        asm volatile("" ::: "memory");

        const ushort_t* rb = cur + (lane << 3);
#pragma unroll
        for (int ks = 0; ks < 2; ++ks) {
            short8 ah[4], al[4], bh[2], bl[2];
#pragma unroll
            for (int lt = 0; lt < 4; ++lt) {
                ah[lt] = *(const short8*)(rb + aoff + lt * 1024 + ks * 512);
                al[lt] = *(const short8*)(rb + 8192 + aoff + lt * 1024 + ks * 512);
            }
#pragma unroll
            for (int pt = 0; pt < 2; ++pt) {
                bh[pt] = *(const short8*)(rb + boff + pt * 1024 + ks * 512);
                bl[pt] = *(const short8*)(rb + 8192 + boff + pt * 1024 + ks * 512);
            }
            __builtin_amdgcn_s_setprio(1);
#pragma unroll
            for (int pt = 0; pt < 2; ++pt)
#pragma unroll
                for (int lt = 0; lt < 4; ++lt) {
                    acc[pt][lt] = __builtin_amdgcn_mfma_f32_32x32x16_bf16(bh[pt], ah[lt], acc[pt][lt], 0, 0, 0);
                    acc[pt][lt] = __builtin_amdgcn_mfma_f32_32x32x16_bf16(bh[pt], al[lt], acc[pt][lt], 0, 0, 0);
                    acc[pt][lt] = __builtin_amdgcn_mfma_f32_32x32x16_bf16(bl[pt], ah[lt], acc[pt][lt], 0, 0, 0);
                }
            __builtin_amdgcn_s_setprio(0);
        }
        ushort_t* tmp = cur; cur = nxt; nxt = tmp;
    }
#undef STAGE

    int x = lane & 31, kg = lane >> 5;
    int pw0 = P0 + (wp << 6);
    int lw0 = L0 + (wl << 7);
#pragma unroll
    for (int pt = 0; pt < 2; ++pt)
#pragma unroll
        for (int lt = 0; lt < 4; ++lt)
#pragma unroll
            for (int r = 0; r < 16; ++r) {
                int p = pw0 + (pt << 5) + (r & 3) + ((r >> 2) << 3) + (kg << 2);
                int l = lw0 + (lt << 5) + x;
                if (p < NP) Rt[((size_t)b * NP + p) * NL + l] = acc[pt][lt][r];
            }
}

// ------- kernel 5: fused diag1 + diag2 + mask + softmax, row output -------
__global__ __launch_bounds__(256) void softmax_fused_kernel(const float* __restrict__ Rt,
                                                            const float* __restrict__ mmkA,
                                                            const float* __restrict__ mmpA,
                                                            float* __restrict__ E) {
    __shared__ float ld0[1024], ld1[1024], ld2[1024];
    __shared__ float red[8];
    int p = blockIdx.x, b = blockIdx.y;
    int ph = p / PHW, pw = p - ph * PHW;
    int t = threadIdx.x;
    int lane = t & 63, w = t >> 6;
    int l0 = t << 2;

    bool okm = (p != 0), okp = (p != 3968);
    int Pm = (ph > 0) ? p - 63 : 3905 + pw;
    int Pp = (ph < 62) ? p + 63 : pw + 1;

    const float* Rb = Rt + (size_t)b * NP * NL;
#define BUILD(dst, q)                                                   \
    do {                                                                \
        const float* base = Rb + (size_t)(q) * NL;                      \
        float4 r = *(const float4*)(base + l0);                         \
        if ((q) > 0) {                                                  \
            const float* pm = base - NL;                                \
            r.x += (l0 > 0) ? pm[l0 - 1] : 0.f;                         \
            r.y += pm[l0];  r.z += pm[l0 + 1];  r.w += pm[l0 + 2];      \
        }                                                               \
        if ((q) < NP - 1) {                                             \
            const float* pp = base + NL;                                \
            r.x += pp[l0 + 1];  r.y += pp[l0 + 2];  r.z += pp[l0 + 3];  \
            r.w += (l0 + 4 < NL) ? pp[l0 + 4] : 0.f;                    \
        }                                                               \
        *(float4*)(dst + l0) = r;                                       \
    } while (0)

    BUILD(ld0, p);
    if (okm) BUILD(ld1, Pm);
    if (okp) BUILD(ld2, Pp);
#undef BUILD
    __syncthreads();

    float4 vc = *(const float4*)(ld0 + l0);
    float4 vm = {0.f, 0.f, 0.f, 0.f}, vp = {0.f, 0.f, 0.f, 0.f};
    if (okm) {
        if (l0 >= 32) vm = *(const float4*)(ld1 + l0 - 32);
        else {
            vm.x = (l0 == 0) ? 0.f : ld1[l0 + 991];
            vm.y = ld1[l0 + 992];
            vm.z = ld1[l0 + 993];
            vm.w = ld1[l0 + 994];
        }
    }
    if (okp) {
        if (l0 < 992) vp = *(const float4*)(ld2 + l0 + 32);
        else {
            vp.x = ld2[l0 - 991];
            vp.y = ld2[l0 - 990];
            vp.z = ld2[l0 - 989];
            vp.w = (l0 + 3 == 1023) ? 0.f : ld2[l0 - 988];
        }
    }
    float mmpv = mmpA[b * NP + p];
    float4 km = *(const float4*)(mmkA + b * NL + l0);
    float lg[4];
    float fsum[4] = {vc.x + vm.x + vp.x, vc.y + vm.y + vp.y,
                     vc.z + vm.z + vp.z, vc.w + vm.w + vp.w};
    float kk[4] = {km.x, km.y, km.z, km.w};
#pragma unroll
    for (int i = 0; i < 4; ++i) {
        float mmv = (((kk[i] > mmpv) && (mmpv > 0.5f)) || (kk[i] == 1.0f)) ? 1.0f : 0.0f;
        lg[i] = fsum[i] * mmv * 10.0f;
    }
    float mx = fmaxf(fmaxf(lg[0], lg[1]), fmaxf(lg[2], lg[3]));
#pragma unroll
    for (int off = 32; off >= 1; off >>= 1) mx = fmaxf(mx, __shfl_xor(mx, off, 64));
    if (lane == 0) red[w] = mx;
    __syncthreads();
    mx = fmaxf(fmaxf(red[0], red[1]), fmaxf(red[2], red[3]));
    float e[4];
    float s = 0.f;
#pragma unroll
    for (int i = 0; i < 4; ++i) { e[i] = expf(lg[i] - mx); s += e[i]; }
#pragma unroll
    for (int off = 32; off >= 1; off >>= 1) s += __shfl_xor(s, off, 64);
    if (lane == 0) red[4 + w] = s;
    __syncthreads();
    float rinv = 1.0f / (red[4] + red[5] + red[6] + red[7]);
    float4 ev = {e[0] * rinv, e[1] * rinv, e[2] * rinv, e[3] * rinv};
    *(float4*)(E + (((size_t)b * NP + p) << 10) + l0) = ev;
}

// ---------------- kernel 6: tiled transpose E[p][l] -> out[l][p] ----------
__global__ __launch_bounds__(256) void transpose_kernel(const float* __restrict__ E,
                                                        float* __restrict__ out) {
    __shared__ float tile[63 * 65];
    int pt = blockIdx.x;       // 0..62 : p0 = pt*63
    int lt = blockIdx.y;       // 0..15 : l0 = lt*64
    int b  = blockIdx.z;
    int t = threadIdx.x;
    int p0 = pt * 63, l0 = lt << 6;
    const float* Eb = E + ((size_t)b * NP << 10);
    {
        int j = t & 63, i4 = t >> 6;
#pragma unroll
        for (int k = 0; k < 16; ++k) {
            int i = (k << 2) + i4;
            if (i < 63) tile[i * 65 + j] = Eb[((size_t)(p0 + i) << 10) + l0 + j];
        }
    }
    __syncthreads();
    {
        int ii = t & 63, jj4 = t >> 6;
        if (ii < 63) {
#pragma unroll
            for (int k = 0; k < 16; ++k) {
                int jj = (k << 2) + jj4;
                out[((size_t)b * NL + l0 + jj) * NP + p0 + ii] = tile[ii * 65 + jj];
            }
        }
    }
}

extern "C" void kernel_launch(void* const* d_in, const int* in_sizes, int n_in,
                              void* d_out, int out_size, void* d_ws, size_t ws_size,
                              hipStream_t stream) {
    const float* f    = (const float*)d_in[0];
    const float* b    = (const float*)d_in[1];
    const float* mask = (const float*)d_in[2];
    float* out = (float*)d_out;

    // Rt lives in d_out (consumed by softmax before transpose overwrites out).
    float* Rt = (float*)d_out;

    // ws layout (floats): E at [16257024 .. 32514048); stats after.
    // A'/B' (~84 MB) occupy ws from 0 but are dead post-GEMM; E region is
    // written only by softmax (after GEMM completes).
    float* wsf = (float*)d_ws;
    float* E  = wsf + 16257024;
    ushort_t* Ahi = (ushort_t*)d_ws;
    ushort_t* Alo = Ahi + (size_t)NB * A_BSTRIDE;
    ushort_t* Bhi = Alo + (size_t)NB * A_BSTRIDE;
    ushort_t* Blo = Bhi + (size_t)NB * B_BSTRIDE;
    float* invn = wsf + 32514048;
    float* mmk = invn + 256;
    float* mmp = mmk + 4096;

    prep_kernel<<<dim3(847), dim3(256), 0, stream>>>(b, mask, invn, mmk, mmp, Bhi, Blo);
    splitA_kernel<<<dim3(32, 4, 2), dim3(256), 0, stream>>>(b, invn, Ahi, Alo);
    splitB_kernel<<<dim3(63, 4, 2), dim3(256), 0, stream>>>(f, Bhi, Blo);
    gemm_kernel<<<dim3(256), dim3(512), 0, stream>>>(Ahi, Alo, Bhi, Blo, Rt);
    softmax_fused_kernel<<<dim3(3969, 4), dim3(256), 0, stream>>>(Rt, mmk, mmp, E);
    transpose_kernel<<<dim3(63, 16, 4), dim3(256), 0, stream>>>(E, out);
}